// Round 6
// baseline (604.527 us; speedup 1.0000x reference)
//
#include <hip/hip_runtime.h>
#include <math.h>

#define N_NODES 100000
#define N_EDGES 3200000
#define D4 16
#define EPS 1e-16f
#define BSH 8
#define BNODES 256
#define NBK 391              /* ceil(100000/256) */
#define PE 16
#define PTILE (PE * 256)
#define NR 4                 /* source ranges (3.2MB bf16 slice each, fits 4MB XCD L2) */

// prop_pass mode flags
#define M_ACCUM  1   /* add P into partial */
#define M_LAST   2   /* final pass of the layer */
#define M_L1     4   /* layer 1: acc = emb + tot */
#define M_FINAL  8   /* layer 3: acc = (acc + tot) * 0.25 */
#define M_WRITEP 16  /* write tot to P (next layer's table) */

static __device__ __forceinline__ unsigned short f_to_bf(float f) {
    unsigned u = __float_as_uint(f);
    unsigned r = (u + 0x7FFFu + ((u >> 16) & 1u)) >> 16;  // RNE
    return (unsigned short)r;
}
static __device__ __forceinline__ float bf_to_f(unsigned short b) {
    return __uint_as_float((unsigned)b << 16);
}
static __device__ __forceinline__ float4 bf4_to_f4(ushort4 u) {
    return make_float4(bf_to_f(u.x), bf_to_f(u.y), bf_to_f(u.z), bf_to_f(u.w));
}
static __device__ __forceinline__ ushort4 f4_to_bf4(float x, float y, float z, float w) {
    return make_ushort4(f_to_bf(x), f_to_bf(y), f_to_bf(z), f_to_bf(w));
}
static __device__ __forceinline__ int range_of(unsigned f) {
    return (f >= 50000u) ? (f >= 75000u ? 3 : 2) : (f >= 25000u ? 1 : 0);
}

// ---- Phase A: exact bucket histograms (per-block LDS, one flush per block) ----
__global__ void hist_kernel(const int* __restrict__ ei,
                            unsigned* __restrict__ cnt_t, unsigned* __restrict__ cnt_f) {
    __shared__ unsigned ht[NBK], hf[NBK];
    for (int i = threadIdx.x; i < NBK; i += 256) { ht[i] = 0; hf[i] = 0; }
    __syncthreads();
    int stride = gridDim.x * blockDim.x;
    for (int e = blockIdx.x * blockDim.x + threadIdx.x; e < N_EDGES; e += stride) {
        atomicAdd(&hf[((unsigned)ei[e]) >> BSH], 1u);
        atomicAdd(&ht[((unsigned)ei[N_EDGES + e]) >> BSH], 1u);
    }
    __syncthreads();
    for (int i = threadIdx.x; i < NBK; i += 256) {
        if (ht[i]) atomicAdd(&cnt_t[i], ht[i]);
        if (hf[i]) atomicAdd(&cnt_f[i], hf[i]);
    }
}

// ---- Phase B: exclusive scan of bucket counts -> bases + reservation cursors ----
__global__ void scan_buckets(const unsigned* __restrict__ cnt_t, const unsigned* __restrict__ cnt_f,
                             unsigned* __restrict__ base_t, unsigned* __restrict__ base_f,
                             unsigned* __restrict__ pos_t, unsigned* __restrict__ pos_f) {
    __shared__ unsigned sc[512];
    int tid = threadIdx.x;
    unsigned own = (tid < NBK) ? cnt_t[tid] : 0u;
    sc[tid] = own;
    __syncthreads();
    for (int o = 1; o < 512; o <<= 1) {
        unsigned v = (tid >= o) ? sc[tid - o] : 0u;
        __syncthreads();
        sc[tid] += v;
        __syncthreads();
    }
    if (tid < NBK) { unsigned ex = sc[tid] - own; base_t[tid] = ex; pos_t[tid] = ex; }
    if (tid == NBK - 1) base_t[NBK] = sc[tid];
    __syncthreads();
    own = (tid < NBK) ? cnt_f[tid] : 0u;
    sc[tid] = own;
    __syncthreads();
    for (int o = 1; o < 512; o <<= 1) {
        unsigned v = (tid >= o) ? sc[tid - o] : 0u;
        __syncthreads();
        sc[tid] += v;
        __syncthreads();
    }
    if (tid < NBK) { unsigned ex = sc[tid] - own; base_f[tid] = ex; pos_f[tid] = ex; }
    if (tid == NBK - 1) base_f[NBK] = sc[tid];
}

// ---- Phase C: single-pass partition into dst-bucketed and src-bucketed arrays ----
__global__ void partition(const int* __restrict__ ei, const float* __restrict__ attr,
                          unsigned* __restrict__ pos_t, unsigned* __restrict__ pos_f,
                          uint2* __restrict__ bt, uint2* __restrict__ bf) {
    __shared__ unsigned ht[NBK], hf[NBK];
    for (int i = threadIdx.x; i < NBK; i += 256) { ht[i] = 0; hf[i] = 0; }
    __syncthreads();
    const int tile = blockIdx.x * PTILE;
    unsigned fv[PE], tv[PE];
    float xv[PE];
    #pragma unroll
    for (int k = 0; k < PE; ++k) {
        int e = tile + k * 256 + threadIdx.x;
        if (e < N_EDGES) {
            fv[k] = (unsigned)ei[e];
            tv[k] = (unsigned)ei[N_EDGES + e];
            xv[k] = __expf(attr[e]);
            atomicAdd(&ht[tv[k] >> BSH], 1u);
            atomicAdd(&hf[fv[k] >> BSH], 1u);
        } else {
            tv[k] = 0xFFFFFFFFu;
        }
    }
    __syncthreads();
    for (int i = threadIdx.x; i < NBK; i += 256) {
        unsigned c = ht[i];
        if (c) ht[i] = atomicAdd(&pos_t[i], c);
        c = hf[i];
        if (c) hf[i] = atomicAdd(&pos_f[i], c);
    }
    __syncthreads();
    #pragma unroll
    for (int k = 0; k < PE; ++k) {
        if (tv[k] != 0xFFFFFFFFu) {
            unsigned p = atomicAdd(&ht[tv[k] >> BSH], 1u);
            bt[p] = make_uint2(fv[k] | ((tv[k] & 255u) << 17), __float_as_uint(xv[k]));
            unsigned q = atomicAdd(&hf[fv[k] >> BSH], 1u);
            bf[q] = make_uint2(fv[k] & 255u, __float_as_uint(xv[k]));
        }
    }
}

// ---- Phase D: per-src-bucket sums -> s_from_inv (LDS only) ----
__global__ void bucket_sum_f(const unsigned* __restrict__ base_f, const uint2* __restrict__ bf,
                             float* __restrict__ s_from_inv) {
    __shared__ float s[BNODES];
    int b = blockIdx.x, tid = threadIdx.x;
    s[tid] = 0.f;
    __syncthreads();
    unsigned lo = base_f[b], hi = base_f[b + 1];
    for (unsigned i = lo + tid; i < hi; i += 256) {
        uint2 u = bf[i];
        atomicAdd(&s[u.x & 255u], __uint_as_float(u.y));
    }
    __syncthreads();
    int node = b * BNODES + tid;
    if (node < N_NODES) s_from_inv[node] = rsqrtf(s[tid] + EPS);
}

// ---- Phase E: per-dst-bucket: range-segmented dense CSR + final edge weights ----
__global__ void bucket_csr_t(const unsigned* __restrict__ base_t, const uint2* __restrict__ bt,
                             const float* __restrict__ s_from_inv,
                             unsigned* __restrict__ rp, uint2* __restrict__ slots) {
    __shared__ unsigned cnt[BNODES][NR];
    __shared__ float sto[BNODES];
    __shared__ unsigned sc[BNODES];
    __shared__ float rs[BNODES];
    __shared__ unsigned cur[BNODES][NR];
    int b = blockIdx.x, tid = threadIdx.x;
    #pragma unroll
    for (int r = 0; r < NR; ++r) cnt[tid][r] = 0;
    sto[tid] = 0.f;
    __syncthreads();
    unsigned lo = base_t[b], hi = base_t[b + 1];
    for (unsigned i = lo + tid; i < hi; i += 256) {
        uint2 u = bt[i];
        unsigned tl = u.x >> 17;
        unsigned f = u.x & 0x1FFFFu;
        atomicAdd(&cnt[tl][range_of(f)], 1u);
        atomicAdd(&sto[tl], __uint_as_float(u.y));
    }
    __syncthreads();
    unsigned c0 = cnt[tid][0], c1 = cnt[tid][1], c2 = cnt[tid][2], c3 = cnt[tid][3];
    unsigned tot = c0 + c1 + c2 + c3;
    sc[tid] = tot;
    __syncthreads();
    for (int o = 1; o < 256; o <<= 1) {
        unsigned v = (tid >= o) ? sc[tid - o] : 0u;
        __syncthreads();
        sc[tid] += v;
        __syncthreads();
    }
    unsigned base0 = lo + sc[tid] - tot;
    int node = b * BNODES + tid;
    if (node < N_NODES) {
        unsigned* r0 = &rp[(size_t)node * NR];
        r0[0] = base0;
        r0[1] = base0 + c0;
        r0[2] = base0 + c0 + c1;
        r0[3] = base0 + c0 + c1 + c2;
    }
    if (b == NBK - 1 && tid == 0) rp[(size_t)N_NODES * NR] = N_EDGES;
    rs[tid] = rsqrtf(sto[tid] + EPS);
    cur[tid][0] = base0;
    cur[tid][1] = base0 + c0;
    cur[tid][2] = base0 + c0 + c1;
    cur[tid][3] = base0 + c0 + c1 + c2;
    __syncthreads();
    for (unsigned i = lo + tid; i < hi; i += 256) {
        uint2 u = bt[i];
        unsigned tl = u.x >> 17;
        unsigned f = u.x & 0x1FFFFu;
        float w = __uint_as_float(u.y) * rs[tl] * s_from_inv[f];
        unsigned p = atomicAdd(&cur[tl][range_of(f)], 1u);
        slots[p] = make_uint2(f, __float_as_uint(w));
    }
}

// ---- emb -> bf16 table + out_emb copy ----
__global__ void emb_cvt(const float4* __restrict__ emb4, float4* __restrict__ out_emb4,
                        ushort4* __restrict__ emb_bf) {
    int i = blockIdx.x * blockDim.x + threadIdx.x;
    if (i >= N_NODES * D4) return;
    float4 v = emb4[i];
    out_emb4[i] = v;
    emb_bf[i] = f4_to_bf4(v.x, v.y, v.z, v.w);
}

// ---- Range-sliced propagation pass: gathers only from a 3.2MB L2-resident slice ----
__global__ void prop_pass(const unsigned* __restrict__ rp, const uint2* __restrict__ slots,
                          const ushort4* __restrict__ table, ushort4* __restrict__ P,
                          const float* __restrict__ emb, float* __restrict__ acc,
                          int r, int mode) {
    int node = blockIdx.x * 16 + (threadIdx.x >> 4);
    int lane = threadIdx.x & 15;
    if (node >= N_NODES) return;
    unsigned beg = rp[(size_t)node * NR + r], end = rp[(size_t)node * NR + r + 1];
    float ax = 0.f, ay = 0.f, az = 0.f, aw = 0.f;
    for (unsigned k = beg; k < end; ++k) {
        uint2 sl = slots[k];
        float w = __uint_as_float(sl.y);
        float4 v = bf4_to_f4(table[(size_t)sl.x * D4 + lane]);
        ax = fmaf(w, v.x, ax); ay = fmaf(w, v.y, ay);
        az = fmaf(w, v.z, az); aw = fmaf(w, v.w, aw);
    }
    size_t o = (size_t)node * D4 + lane;
    if (mode & M_ACCUM) {
        float4 p = bf4_to_f4(P[o]);
        ax += p.x; ay += p.y; az += p.z; aw += p.w;
    }
    if (!(mode & M_LAST)) {
        P[o] = f4_to_bf4(ax, ay, az, aw);
        return;
    }
    if (mode & M_L1) {
        float4 e = ((const float4*)emb)[o];
        ((float4*)acc)[o] = make_float4(e.x + ax, e.y + ay, e.z + az, e.w + aw);
    } else if (mode & M_FINAL) {
        float4 c = ((float4*)acc)[o];
        ((float4*)acc)[o] = make_float4((c.x + ax) * 0.25f, (c.y + ay) * 0.25f,
                                        (c.z + az) * 0.25f, (c.w + aw) * 0.25f);
    } else {
        float4 c = ((float4*)acc)[o];
        ((float4*)acc)[o] = make_float4(c.x + ax, c.y + ay, c.z + az, c.w + aw);
    }
    if (mode & M_WRITEP) P[o] = f4_to_bf4(ax, ay, az, aw);
}

extern "C" void kernel_launch(void* const* d_in, const int* in_sizes, int n_in,
                              void* d_out, int out_size, void* d_ws, size_t ws_size,
                              hipStream_t stream) {
    const float* emb = (const float*)d_in[0];
    const int* ei = (const int*)d_in[1];
    const float* attr = (const float*)d_in[2];

    float* out_emb = (float*)d_out;
    float* out_acc = out_emb + (size_t)N_NODES * 64;

    char* ws = (char*)d_ws;
    size_t off = 0;
    auto alloc = [&](size_t bytes) -> void* {
        void* p = ws + off;
        off += (bytes + 255) & ~(size_t)255;
        return p;
    };
    unsigned* cnt_t   = (unsigned*)alloc((size_t)NBK * 4);
    unsigned* cnt_f   = (unsigned*)alloc((size_t)NBK * 4);
    size_t zero_bytes = off;
    unsigned* base_t  = (unsigned*)alloc((size_t)(NBK + 1) * 4);
    unsigned* base_f  = (unsigned*)alloc((size_t)(NBK + 1) * 4);
    unsigned* pos_t   = (unsigned*)alloc((size_t)NBK * 4);
    unsigned* pos_f   = (unsigned*)alloc((size_t)NBK * 4);
    unsigned* rp      = (unsigned*)alloc(((size_t)N_NODES * NR + 1) * 4);
    float* s_from_inv = (float*)   alloc((size_t)N_NODES * 4);
    uint2* bt         = (uint2*)   alloc((size_t)N_EDGES * 8);   // later: [T2 | emb_bf]
    uint2* bf         = (uint2*)   alloc((size_t)N_EDGES * 8);   // later: slots
    uint2* slots      = bf;        // bf fully consumed by bucket_sum_f before slots written
    ushort4* T1       = (ushort4*) alloc((size_t)N_NODES * 64 * 2);
    // aliases inside the dead bt region (bt consumed by bucket_csr_t):
    ushort4* T2     = (ushort4*)bt;                                   // layer-2 output table
    ushort4* emb_bf = (ushort4*)((char*)bt + (size_t)N_NODES * 128);  // bf16 emb, then layer-3 P scratch
    (void)ws_size;

    hipMemsetAsync(d_ws, 0, zero_bytes, stream);

    hist_kernel<<<256, 256, 0, stream>>>(ei, cnt_t, cnt_f);
    scan_buckets<<<1, 512, 0, stream>>>(cnt_t, cnt_f, base_t, base_f, pos_t, pos_f);
    const int pblocks = (N_EDGES + PTILE - 1) / PTILE;
    partition<<<pblocks, 256, 0, stream>>>(ei, attr, pos_t, pos_f, bt, bf);
    bucket_sum_f<<<NBK, 256, 0, stream>>>(base_f, bf, s_from_inv);
    bucket_csr_t<<<NBK, 256, 0, stream>>>(base_t, bt, s_from_inv, rp, slots);

    const int vgrid = (N_NODES * D4 + 255) / 256;
    emb_cvt<<<vgrid, 256, 0, stream>>>((const float4*)emb, (float4*)out_emb, emb_bf);

    const int pgrid = (N_NODES * 16 + 255) / 256;
    // Layer 1: table=emb_bf, P=T1; last pass: acc = emb + tot, write T1
    prop_pass<<<pgrid, 256, 0, stream>>>(rp, slots, emb_bf, T1, emb, out_acc, 0, 0);
    prop_pass<<<pgrid, 256, 0, stream>>>(rp, slots, emb_bf, T1, emb, out_acc, 1, M_ACCUM);
    prop_pass<<<pgrid, 256, 0, stream>>>(rp, slots, emb_bf, T1, emb, out_acc, 2, M_ACCUM);
    prop_pass<<<pgrid, 256, 0, stream>>>(rp, slots, emb_bf, T1, emb, out_acc, 3,
                                         M_ACCUM | M_LAST | M_L1 | M_WRITEP);
    // Layer 2: table=T1, P=T2; last pass: acc += tot, write T2
    prop_pass<<<pgrid, 256, 0, stream>>>(rp, slots, T1, T2, emb, out_acc, 0, 0);
    prop_pass<<<pgrid, 256, 0, stream>>>(rp, slots, T1, T2, emb, out_acc, 1, M_ACCUM);
    prop_pass<<<pgrid, 256, 0, stream>>>(rp, slots, T1, T2, emb, out_acc, 2, M_ACCUM);
    prop_pass<<<pgrid, 256, 0, stream>>>(rp, slots, T1, T2, emb, out_acc, 3,
                                         M_ACCUM | M_LAST | M_WRITEP);
    // Layer 3: table=T2, P=emb_bf (scratch); last pass: acc = (acc + tot) * 0.25
    prop_pass<<<pgrid, 256, 0, stream>>>(rp, slots, T2, emb_bf, emb, out_acc, 0, 0);
    prop_pass<<<pgrid, 256, 0, stream>>>(rp, slots, T2, emb_bf, emb, out_acc, 1, M_ACCUM);
    prop_pass<<<pgrid, 256, 0, stream>>>(rp, slots, T2, emb_bf, emb, out_acc, 2, M_ACCUM);
    prop_pass<<<pgrid, 256, 0, stream>>>(rp, slots, T2, emb_bf, emb, out_acc, 3,
                                         M_ACCUM | M_LAST | M_FINAL);
}

// Round 7
// 512.457 us; speedup vs baseline: 1.1797x; 1.1797x over previous
//
#include <hip/hip_runtime.h>
#include <math.h>

#define N_NODES 100000
#define N_EDGES 3200000
#define D4 16
#define EPS 1e-16f
#define BSH 8
#define BNODES 256
#define NBK 391              /* ceil(100000/256) */
#define PE 16
#define PTILE (PE * 256)

static __device__ __forceinline__ unsigned short f_to_bf(float f) {
    unsigned u = __float_as_uint(f);
    unsigned r = (u + 0x7FFFu + ((u >> 16) & 1u)) >> 16;  // RNE
    return (unsigned short)r;
}
static __device__ __forceinline__ float bf_to_f(unsigned short b) {
    return __uint_as_float((unsigned)b << 16);
}
static __device__ __forceinline__ float4 bf4_to_f4(ushort4 u) {
    return make_float4(bf_to_f(u.x), bf_to_f(u.y), bf_to_f(u.z), bf_to_f(u.w));
}
static __device__ __forceinline__ ushort4 f4_to_bf4(float x, float y, float z, float w) {
    return make_ushort4(f_to_bf(x), f_to_bf(y), f_to_bf(z), f_to_bf(w));
}

// ---- Phase A: exact bucket histograms (per-block LDS, one flush per block) ----
__global__ void hist_kernel(const int* __restrict__ ei,
                            unsigned* __restrict__ cnt_t, unsigned* __restrict__ cnt_f) {
    __shared__ unsigned ht[NBK], hf[NBK];
    for (int i = threadIdx.x; i < NBK; i += 256) { ht[i] = 0; hf[i] = 0; }
    __syncthreads();
    int stride = gridDim.x * blockDim.x;
    for (int e = blockIdx.x * blockDim.x + threadIdx.x; e < N_EDGES; e += stride) {
        atomicAdd(&hf[((unsigned)ei[e]) >> BSH], 1u);
        atomicAdd(&ht[((unsigned)ei[N_EDGES + e]) >> BSH], 1u);
    }
    __syncthreads();
    for (int i = threadIdx.x; i < NBK; i += 256) {
        if (ht[i]) atomicAdd(&cnt_t[i], ht[i]);
        if (hf[i]) atomicAdd(&cnt_f[i], hf[i]);
    }
}

// ---- Phase B: exclusive scan of bucket counts -> bases + reservation cursors ----
__global__ void scan_buckets(const unsigned* __restrict__ cnt_t, const unsigned* __restrict__ cnt_f,
                             unsigned* __restrict__ base_t, unsigned* __restrict__ base_f,
                             unsigned* __restrict__ pos_t, unsigned* __restrict__ pos_f) {
    __shared__ unsigned sc[512];
    int tid = threadIdx.x;
    unsigned own = (tid < NBK) ? cnt_t[tid] : 0u;
    sc[tid] = own;
    __syncthreads();
    for (int o = 1; o < 512; o <<= 1) {
        unsigned v = (tid >= o) ? sc[tid - o] : 0u;
        __syncthreads();
        sc[tid] += v;
        __syncthreads();
    }
    if (tid < NBK) { unsigned ex = sc[tid] - own; base_t[tid] = ex; pos_t[tid] = ex; }
    if (tid == NBK - 1) base_t[NBK] = sc[tid];
    __syncthreads();
    own = (tid < NBK) ? cnt_f[tid] : 0u;
    sc[tid] = own;
    __syncthreads();
    for (int o = 1; o < 512; o <<= 1) {
        unsigned v = (tid >= o) ? sc[tid - o] : 0u;
        __syncthreads();
        sc[tid] += v;
        __syncthreads();
    }
    if (tid < NBK) { unsigned ex = sc[tid] - own; base_f[tid] = ex; pos_f[tid] = ex; }
    if (tid == NBK - 1) base_f[NBK] = sc[tid];
}

// ---- Phase C: single-pass partition into dst-bucketed and src-bucketed arrays ----
__global__ void partition(const int* __restrict__ ei, const float* __restrict__ attr,
                          unsigned* __restrict__ pos_t, unsigned* __restrict__ pos_f,
                          uint2* __restrict__ bt, uint2* __restrict__ bf) {
    __shared__ unsigned ht[NBK], hf[NBK];
    for (int i = threadIdx.x; i < NBK; i += 256) { ht[i] = 0; hf[i] = 0; }
    __syncthreads();
    const int tile = blockIdx.x * PTILE;
    unsigned fv[PE], tv[PE];
    float xv[PE];
    #pragma unroll
    for (int k = 0; k < PE; ++k) {
        int e = tile + k * 256 + threadIdx.x;
        if (e < N_EDGES) {
            fv[k] = (unsigned)ei[e];
            tv[k] = (unsigned)ei[N_EDGES + e];
            xv[k] = __expf(attr[e]);
            atomicAdd(&ht[tv[k] >> BSH], 1u);
            atomicAdd(&hf[fv[k] >> BSH], 1u);
        } else {
            tv[k] = 0xFFFFFFFFu;
        }
    }
    __syncthreads();
    for (int i = threadIdx.x; i < NBK; i += 256) {
        unsigned c = ht[i];
        if (c) ht[i] = atomicAdd(&pos_t[i], c);
        c = hf[i];
        if (c) hf[i] = atomicAdd(&pos_f[i], c);
    }
    __syncthreads();
    #pragma unroll
    for (int k = 0; k < PE; ++k) {
        if (tv[k] != 0xFFFFFFFFu) {
            unsigned p = atomicAdd(&ht[tv[k] >> BSH], 1u);
            bt[p] = make_uint2(fv[k] | ((tv[k] & 255u) << 17), __float_as_uint(xv[k]));
            unsigned q = atomicAdd(&hf[fv[k] >> BSH], 1u);
            bf[q] = make_uint2(fv[k] & 255u, __float_as_uint(xv[k]));
        }
    }
}

// ---- Phase D: per-src-bucket sums -> s_from_inv (LDS only) ----
__global__ void bucket_sum_f(const unsigned* __restrict__ base_f, const uint2* __restrict__ bf,
                             float* __restrict__ s_from_inv) {
    __shared__ float s[BNODES];
    int b = blockIdx.x, tid = threadIdx.x;
    s[tid] = 0.f;
    __syncthreads();
    unsigned lo = base_f[b], hi = base_f[b + 1];
    for (unsigned i = lo + tid; i < hi; i += 256) {
        uint2 u = bf[i];
        atomicAdd(&s[u.x & 255u], __uint_as_float(u.y));
    }
    __syncthreads();
    int node = b * BNODES + tid;
    if (node < N_NODES) s_from_inv[node] = rsqrtf(s[tid] + EPS);
}

// ---- Phase E: per-dst-bucket: exact dense CSR (row_ptr) + final edge weights ----
__global__ void bucket_csr_t(const unsigned* __restrict__ base_t, const uint2* __restrict__ bt,
                             const float* __restrict__ s_from_inv,
                             unsigned* __restrict__ row_ptr, uint2* __restrict__ slots) {
    __shared__ unsigned cnt[BNODES];
    __shared__ float sto[BNODES];
    __shared__ unsigned sc[BNODES];
    __shared__ float rs[BNODES];
    __shared__ unsigned cur[BNODES];
    int b = blockIdx.x, tid = threadIdx.x;
    cnt[tid] = 0;
    sto[tid] = 0.f;
    __syncthreads();
    unsigned lo = base_t[b], hi = base_t[b + 1];
    for (unsigned i = lo + tid; i < hi; i += 256) {
        uint2 u = bt[i];
        unsigned tl = u.x >> 17;
        atomicAdd(&cnt[tl], 1u);
        atomicAdd(&sto[tl], __uint_as_float(u.y));
    }
    __syncthreads();
    unsigned own = cnt[tid];
    sc[tid] = own;
    __syncthreads();
    for (int o = 1; o < 256; o <<= 1) {
        unsigned v = (tid >= o) ? sc[tid - o] : 0u;
        __syncthreads();
        sc[tid] += v;
        __syncthreads();
    }
    unsigned excl = sc[tid] - own;
    int node = b * BNODES + tid;
    if (node < N_NODES) row_ptr[node] = lo + excl;
    if (b == NBK - 1 && tid == 0) row_ptr[N_NODES] = N_EDGES;
    rs[tid] = rsqrtf(sto[tid] + EPS);
    cur[tid] = lo + excl;
    __syncthreads();
    for (unsigned i = lo + tid; i < hi; i += 256) {
        uint2 u = bt[i];
        unsigned tl = u.x >> 17;
        unsigned f = u.x & 0x1FFFFu;
        float w = __uint_as_float(u.y) * rs[tl] * s_from_inv[f];
        unsigned p = atomicAdd(&cur[tl], 1u);
        slots[p] = make_uint2(f, __float_as_uint(w));
    }
}

// ---- emb -> bf16 table + out_emb copy (runs after bucket_csr_t; emb_bf aliases bt) ----
__global__ void emb_cvt(const float4* __restrict__ emb4, float4* __restrict__ out_emb4,
                        ushort4* __restrict__ emb_bf) {
    int i = blockIdx.x * blockDim.x + threadIdx.x;
    if (i >= N_NODES * D4) return;
    float4 v = emb4[i];
    out_emb4[i] = v;
    emb_bf[i] = f4_to_bf4(v.x, v.y, v.z, v.w);
}

// ---- Layer 1: bf16 emb gather; T1 = bf16(l1); acc = emb + l1 (f32, write-only) ----
__global__ void prop1(const unsigned* __restrict__ row_ptr, const uint2* __restrict__ slots,
                      const ushort4* __restrict__ emb_bf, const float4* __restrict__ emb4,
                      ushort4* __restrict__ T1, float4* __restrict__ acc) {
    int node = blockIdx.x * 16 + (threadIdx.x >> 4);
    int lane = threadIdx.x & 15;
    if (node >= N_NODES) return;
    unsigned beg = row_ptr[node], end = row_ptr[node + 1];
    float ax = 0.f, ay = 0.f, az = 0.f, aw = 0.f;
    for (unsigned k = beg; k < end; ++k) {
        uint2 sl = slots[k];
        float w = __uint_as_float(sl.y);
        float4 v = bf4_to_f4(emb_bf[(size_t)sl.x * D4 + lane]);
        ax = fmaf(w, v.x, ax); ay = fmaf(w, v.y, ay);
        az = fmaf(w, v.z, az); aw = fmaf(w, v.w, aw);
    }
    size_t o = (size_t)node * D4 + lane;
    T1[o] = f4_to_bf4(ax, ay, az, aw);
    float4 e = emb4[o];
    acc[o] = make_float4(e.x + ax, e.y + ay, e.z + az, e.w + aw);
}

// ---- Layer 2: bf16 gather from T1; writes T2 only (acc deferred to layer 3) ----
__global__ void prop2(const unsigned* __restrict__ row_ptr, const uint2* __restrict__ slots,
                      const ushort4* __restrict__ T1, ushort4* __restrict__ T2) {
    int node = blockIdx.x * 16 + (threadIdx.x >> 4);
    int lane = threadIdx.x & 15;
    if (node >= N_NODES) return;
    unsigned beg = row_ptr[node], end = row_ptr[node + 1];
    float ax = 0.f, ay = 0.f, az = 0.f, aw = 0.f;
    for (unsigned k = beg; k < end; ++k) {
        uint2 sl = slots[k];
        float w = __uint_as_float(sl.y);
        float4 v = bf4_to_f4(T1[(size_t)sl.x * D4 + lane]);
        ax = fmaf(w, v.x, ax); ay = fmaf(w, v.y, ay);
        az = fmaf(w, v.z, az); aw = fmaf(w, v.w, aw);
    }
    size_t o = (size_t)node * D4 + lane;
    T2[o] = f4_to_bf4(ax, ay, az, aw);
}

// ---- Layer 3: bf16 gather from T2; acc = (acc + T2[o] + l3) * 0.25 ----
__global__ void prop3(const unsigned* __restrict__ row_ptr, const uint2* __restrict__ slots,
                      const ushort4* __restrict__ T2, float4* __restrict__ acc) {
    int node = blockIdx.x * 16 + (threadIdx.x >> 4);
    int lane = threadIdx.x & 15;
    if (node >= N_NODES) return;
    unsigned beg = row_ptr[node], end = row_ptr[node + 1];
    float ax = 0.f, ay = 0.f, az = 0.f, aw = 0.f;
    for (unsigned k = beg; k < end; ++k) {
        uint2 sl = slots[k];
        float w = __uint_as_float(sl.y);
        float4 v = bf4_to_f4(T2[(size_t)sl.x * D4 + lane]);
        ax = fmaf(w, v.x, ax); ay = fmaf(w, v.y, ay);
        az = fmaf(w, v.z, az); aw = fmaf(w, v.w, aw);
    }
    size_t o = (size_t)node * D4 + lane;
    float4 l2 = bf4_to_f4(T2[o]);
    float4 c = acc[o];
    acc[o] = make_float4((c.x + l2.x + ax) * 0.25f, (c.y + l2.y + ay) * 0.25f,
                         (c.z + l2.z + az) * 0.25f, (c.w + l2.w + aw) * 0.25f);
}

extern "C" void kernel_launch(void* const* d_in, const int* in_sizes, int n_in,
                              void* d_out, int out_size, void* d_ws, size_t ws_size,
                              hipStream_t stream) {
    const float* emb = (const float*)d_in[0];
    const int* ei = (const int*)d_in[1];
    const float* attr = (const float*)d_in[2];

    float* out_emb = (float*)d_out;
    float* out_acc = out_emb + (size_t)N_NODES * 64;

    char* ws = (char*)d_ws;
    size_t off = 0;
    auto alloc = [&](size_t bytes) -> void* {
        void* p = ws + off;
        off += (bytes + 255) & ~(size_t)255;
        return p;
    };
    unsigned* cnt_t   = (unsigned*)alloc((size_t)NBK * 4);
    unsigned* cnt_f   = (unsigned*)alloc((size_t)NBK * 4);
    size_t zero_bytes = off;
    unsigned* base_t  = (unsigned*)alloc((size_t)(NBK + 1) * 4);
    unsigned* base_f  = (unsigned*)alloc((size_t)(NBK + 1) * 4);
    unsigned* pos_t   = (unsigned*)alloc((size_t)NBK * 4);
    unsigned* pos_f   = (unsigned*)alloc((size_t)NBK * 4);
    unsigned* row_ptr = (unsigned*)alloc((size_t)(N_NODES + 1) * 4);
    float* s_from_inv = (float*)   alloc((size_t)N_NODES * 4);
    uint2* bt         = (uint2*)   alloc((size_t)N_EDGES * 8);   // dead after bucket_csr_t
    uint2* bf         = (uint2*)   alloc((size_t)N_EDGES * 8);   // becomes slots
    uint2* slots      = bf;        // bf fully consumed by bucket_sum_f before slots written
    ushort4* T1       = (ushort4*) alloc((size_t)N_NODES * 64 * 2);
    // aliases inside the dead bt region:
    ushort4* T2     = (ushort4*)bt;                                   // layer-2 output table
    ushort4* emb_bf = (ushort4*)((char*)bt + (size_t)N_NODES * 128);  // bf16 emb table
    (void)ws_size;

    hipMemsetAsync(d_ws, 0, zero_bytes, stream);

    hist_kernel<<<256, 256, 0, stream>>>(ei, cnt_t, cnt_f);
    scan_buckets<<<1, 512, 0, stream>>>(cnt_t, cnt_f, base_t, base_f, pos_t, pos_f);
    const int pblocks = (N_EDGES + PTILE - 1) / PTILE;
    partition<<<pblocks, 256, 0, stream>>>(ei, attr, pos_t, pos_f, bt, bf);
    bucket_sum_f<<<NBK, 256, 0, stream>>>(base_f, bf, s_from_inv);
    bucket_csr_t<<<NBK, 256, 0, stream>>>(base_t, bt, s_from_inv, row_ptr, slots);

    const int vgrid = (N_NODES * D4 + 255) / 256;
    emb_cvt<<<vgrid, 256, 0, stream>>>((const float4*)emb, (float4*)out_emb, emb_bf);

    const int pgrid = (N_NODES * 16 + 255) / 256;
    prop1<<<pgrid, 256, 0, stream>>>(row_ptr, slots, emb_bf, (const float4*)emb,
                                     T1, (float4*)out_acc);
    prop2<<<pgrid, 256, 0, stream>>>(row_ptr, slots, T1, T2);
    prop3<<<pgrid, 256, 0, stream>>>(row_ptr, slots, T2, (float4*)out_acc);
}

// Round 8
// 401.887 us; speedup vs baseline: 1.5042x; 1.2751x over previous
//
#include <hip/hip_runtime.h>
#include <math.h>

#define N_NODES 100000
#define N_EDGES 3200000
#define D4 16
#define EPS 1e-16f
#define BSH 8
#define BNODES 256
#define NBK 391              /* ceil(100000/256) */
#define PTILE 8192           /* edges per partition block (two-pass over tile) */

static __device__ __forceinline__ unsigned short f_to_bf(float f) {
    unsigned u = __float_as_uint(f);
    unsigned r = (u + 0x7FFFu + ((u >> 16) & 1u)) >> 16;  // RNE
    return (unsigned short)r;
}
static __device__ __forceinline__ float bf_to_f(unsigned short b) {
    return __uint_as_float((unsigned)b << 16);
}
static __device__ __forceinline__ float4 bf4_to_f4(ushort4 u) {
    return make_float4(bf_to_f(u.x), bf_to_f(u.y), bf_to_f(u.z), bf_to_f(u.w));
}
static __device__ __forceinline__ ushort4 f4_to_bf4(float x, float y, float z, float w) {
    return make_ushort4(f_to_bf(x), f_to_bf(y), f_to_bf(z), f_to_bf(w));
}

// ---- Phase A: exact bucket histograms (per-block LDS, one flush per block) ----
__global__ void hist_kernel(const int* __restrict__ ei,
                            unsigned* __restrict__ cnt_t, unsigned* __restrict__ cnt_f) {
    __shared__ unsigned ht[NBK], hf[NBK];
    for (int i = threadIdx.x; i < NBK; i += 256) { ht[i] = 0; hf[i] = 0; }
    __syncthreads();
    int stride = gridDim.x * blockDim.x;
    for (int e = blockIdx.x * blockDim.x + threadIdx.x; e < N_EDGES; e += stride) {
        atomicAdd(&hf[((unsigned)ei[e]) >> BSH], 1u);
        atomicAdd(&ht[((unsigned)ei[N_EDGES + e]) >> BSH], 1u);
    }
    __syncthreads();
    for (int i = threadIdx.x; i < NBK; i += 256) {
        if (ht[i]) atomicAdd(&cnt_t[i], ht[i]);
        if (hf[i]) atomicAdd(&cnt_f[i], hf[i]);
    }
}

// ---- Phase B: exclusive scan of bucket counts -> bases + reservation cursors ----
__global__ void scan_buckets(const unsigned* __restrict__ cnt_t, const unsigned* __restrict__ cnt_f,
                             unsigned* __restrict__ base_t, unsigned* __restrict__ base_f,
                             unsigned* __restrict__ pos_t, unsigned* __restrict__ pos_f) {
    __shared__ unsigned sc[512];
    int tid = threadIdx.x;
    unsigned own = (tid < NBK) ? cnt_t[tid] : 0u;
    sc[tid] = own;
    __syncthreads();
    for (int o = 1; o < 512; o <<= 1) {
        unsigned v = (tid >= o) ? sc[tid - o] : 0u;
        __syncthreads();
        sc[tid] += v;
        __syncthreads();
    }
    if (tid < NBK) { unsigned ex = sc[tid] - own; base_t[tid] = ex; pos_t[tid] = ex; }
    if (tid == NBK - 1) base_t[NBK] = sc[tid];
    __syncthreads();
    own = (tid < NBK) ? cnt_f[tid] : 0u;
    sc[tid] = own;
    __syncthreads();
    for (int o = 1; o < 512; o <<= 1) {
        unsigned v = (tid >= o) ? sc[tid - o] : 0u;
        __syncthreads();
        sc[tid] += v;
        __syncthreads();
    }
    if (tid < NBK) { unsigned ex = sc[tid] - own; base_f[tid] = ex; pos_f[tid] = ex; }
    if (tid == NBK - 1) base_f[NBK] = sc[tid];
}

// ---- Phase C: partition into dst-bucketed and src-bucketed arrays.
// Two passes over an 8192-edge tile (hist, then write); runs avg ~21 edges. ----
__global__ void partition(const int* __restrict__ ei, const float* __restrict__ attr,
                          unsigned* __restrict__ pos_t, unsigned* __restrict__ pos_f,
                          uint2* __restrict__ bt, uint2* __restrict__ bf) {
    __shared__ unsigned ht[NBK], hf[NBK];
    for (int i = threadIdx.x; i < NBK; i += 256) { ht[i] = 0; hf[i] = 0; }
    __syncthreads();
    const int tile = blockIdx.x * PTILE;
    const int tend = (tile + PTILE < N_EDGES) ? tile + PTILE : N_EDGES;
    for (int e = tile + threadIdx.x; e < tend; e += 256) {
        atomicAdd(&hf[((unsigned)ei[e]) >> BSH], 1u);
        atomicAdd(&ht[((unsigned)ei[N_EDGES + e]) >> BSH], 1u);
    }
    __syncthreads();
    for (int i = threadIdx.x; i < NBK; i += 256) {
        unsigned c = ht[i];
        if (c) ht[i] = atomicAdd(&pos_t[i], c);
        c = hf[i];
        if (c) hf[i] = atomicAdd(&pos_f[i], c);
    }
    __syncthreads();
    for (int e = tile + threadIdx.x; e < tend; e += 256) {
        unsigned f = (unsigned)ei[e];
        unsigned t = (unsigned)ei[N_EDGES + e];
        float x = __expf(attr[e]);
        unsigned p = atomicAdd(&ht[t >> BSH], 1u);
        bt[p] = make_uint2(f | ((t & 255u) << 17), __float_as_uint(x));
        unsigned q = atomicAdd(&hf[f >> BSH], 1u);
        bf[q] = make_uint2(f & 255u, __float_as_uint(x));
    }
}

// ---- Phase D: per-src-bucket sums -> s_from_inv (LDS only) ----
__global__ void bucket_sum_f(const unsigned* __restrict__ base_f, const uint2* __restrict__ bf,
                             float* __restrict__ s_from_inv) {
    __shared__ float s[BNODES];
    int b = blockIdx.x, tid = threadIdx.x;
    s[tid] = 0.f;
    __syncthreads();
    unsigned lo = base_f[b], hi = base_f[b + 1];
    for (unsigned i = lo + tid; i < hi; i += 256) {
        uint2 u = bf[i];
        atomicAdd(&s[u.x & 255u], __uint_as_float(u.y));
    }
    __syncthreads();
    int node = b * BNODES + tid;
    if (node < N_NODES) s_from_inv[node] = rsqrtf(s[tid] + EPS);
}

// ---- Phase E: per-dst-bucket: exact dense CSR (row_ptr) + final edge weights ----
__global__ void bucket_csr_t(const unsigned* __restrict__ base_t, const uint2* __restrict__ bt,
                             const float* __restrict__ s_from_inv,
                             unsigned* __restrict__ row_ptr, uint2* __restrict__ slots) {
    __shared__ unsigned cnt[BNODES];
    __shared__ float sto[BNODES];
    __shared__ unsigned sc[BNODES];
    __shared__ float rs[BNODES];
    __shared__ unsigned cur[BNODES];
    int b = blockIdx.x, tid = threadIdx.x;
    cnt[tid] = 0;
    sto[tid] = 0.f;
    __syncthreads();
    unsigned lo = base_t[b], hi = base_t[b + 1];
    for (unsigned i = lo + tid; i < hi; i += 256) {
        uint2 u = bt[i];
        unsigned tl = u.x >> 17;
        atomicAdd(&cnt[tl], 1u);
        atomicAdd(&sto[tl], __uint_as_float(u.y));
    }
    __syncthreads();
    unsigned own = cnt[tid];
    sc[tid] = own;
    __syncthreads();
    for (int o = 1; o < 256; o <<= 1) {
        unsigned v = (tid >= o) ? sc[tid - o] : 0u;
        __syncthreads();
        sc[tid] += v;
        __syncthreads();
    }
    unsigned excl = sc[tid] - own;
    int node = b * BNODES + tid;
    if (node < N_NODES) row_ptr[node] = lo + excl;
    if (b == NBK - 1 && tid == 0) row_ptr[N_NODES] = N_EDGES;
    rs[tid] = rsqrtf(sto[tid] + EPS);
    cur[tid] = lo + excl;
    __syncthreads();
    for (unsigned i = lo + tid; i < hi; i += 256) {
        uint2 u = bt[i];
        unsigned tl = u.x >> 17;
        unsigned f = u.x & 0x1FFFFu;
        float w = __uint_as_float(u.y) * rs[tl] * s_from_inv[f];
        unsigned p = atomicAdd(&cur[tl], 1u);
        slots[p] = make_uint2(f, __float_as_uint(w));
    }
}

// ---- emb -> bf16 table + out_emb copy ----
__global__ void emb_cvt(const float4* __restrict__ emb4, float4* __restrict__ out_emb4,
                        ushort4* __restrict__ emb_bf) {
    int i = blockIdx.x * blockDim.x + threadIdx.x;
    if (i >= N_NODES * D4) return;
    float4 v = emb4[i];
    out_emb4[i] = v;
    emb_bf[i] = f4_to_bf4(v.x, v.y, v.z, v.w);
}

// 4x-unrolled bf16 gather accumulation core (16 lanes per node)
#define GATHER_CORE(TABLE)                                                        \
    float ax = 0.f, ay = 0.f, az = 0.f, aw = 0.f;                                 \
    float bx = 0.f, by = 0.f, bz = 0.f, bw = 0.f;                                 \
    unsigned k = beg;                                                             \
    for (; k + 4 <= end; k += 4) {                                                \
        uint2 s0 = slots[k], s1 = slots[k + 1], s2 = slots[k + 2], s3 = slots[k + 3]; \
        ushort4 r0 = TABLE[(size_t)s0.x * D4 + lane];                             \
        ushort4 r1 = TABLE[(size_t)s1.x * D4 + lane];                             \
        ushort4 r2 = TABLE[(size_t)s2.x * D4 + lane];                             \
        ushort4 r3 = TABLE[(size_t)s3.x * D4 + lane];                             \
        float w0 = __uint_as_float(s0.y), w1 = __uint_as_float(s1.y);             \
        float w2 = __uint_as_float(s2.y), w3 = __uint_as_float(s3.y);             \
        float4 v0 = bf4_to_f4(r0), v1 = bf4_to_f4(r1);                            \
        float4 v2 = bf4_to_f4(r2), v3 = bf4_to_f4(r3);                            \
        ax = fmaf(w0, v0.x, ax); ay = fmaf(w0, v0.y, ay);                         \
        az = fmaf(w0, v0.z, az); aw = fmaf(w0, v0.w, aw);                         \
        bx = fmaf(w1, v1.x, bx); by = fmaf(w1, v1.y, by);                         \
        bz = fmaf(w1, v1.z, bz); bw = fmaf(w1, v1.w, bw);                         \
        ax = fmaf(w2, v2.x, ax); ay = fmaf(w2, v2.y, ay);                         \
        az = fmaf(w2, v2.z, az); aw = fmaf(w2, v2.w, aw);                         \
        bx = fmaf(w3, v3.x, bx); by = fmaf(w3, v3.y, by);                         \
        bz = fmaf(w3, v3.z, bz); bw = fmaf(w3, v3.w, bw);                         \
    }                                                                             \
    for (; k < end; ++k) {                                                        \
        uint2 sl = slots[k];                                                      \
        float w = __uint_as_float(sl.y);                                          \
        float4 v = bf4_to_f4(TABLE[(size_t)sl.x * D4 + lane]);                    \
        ax = fmaf(w, v.x, ax); ay = fmaf(w, v.y, ay);                             \
        az = fmaf(w, v.z, az); aw = fmaf(w, v.w, aw);                             \
    }                                                                             \
    ax += bx; ay += by; az += bz; aw += bw;

// ---- Layer 1: bf16 emb gather; T1 = bf16(l1); acc = emb + l1 (f32, write-only) ----
__global__ void prop1(const unsigned* __restrict__ row_ptr, const uint2* __restrict__ slots,
                      const ushort4* __restrict__ emb_bf, const float4* __restrict__ emb4,
                      ushort4* __restrict__ T1, float4* __restrict__ acc) {
    int node = blockIdx.x * 16 + (threadIdx.x >> 4);
    int lane = threadIdx.x & 15;
    if (node >= N_NODES) return;
    unsigned beg = row_ptr[node], end = row_ptr[node + 1];
    GATHER_CORE(emb_bf)
    size_t o = (size_t)node * D4 + lane;
    T1[o] = f4_to_bf4(ax, ay, az, aw);
    float4 e = emb4[o];
    acc[o] = make_float4(e.x + ax, e.y + ay, e.z + az, e.w + aw);
}

// ---- Layer 2: bf16 gather from T1; writes T2 only (acc deferred to layer 3) ----
__global__ void prop2(const unsigned* __restrict__ row_ptr, const uint2* __restrict__ slots,
                      const ushort4* __restrict__ T1, ushort4* __restrict__ T2) {
    int node = blockIdx.x * 16 + (threadIdx.x >> 4);
    int lane = threadIdx.x & 15;
    if (node >= N_NODES) return;
    unsigned beg = row_ptr[node], end = row_ptr[node + 1];
    GATHER_CORE(T1)
    size_t o = (size_t)node * D4 + lane;
    T2[o] = f4_to_bf4(ax, ay, az, aw);
}

// ---- Layer 3: bf16 gather from T2; acc = (acc + T2[o] + l3) * 0.25 ----
__global__ void prop3(const unsigned* __restrict__ row_ptr, const uint2* __restrict__ slots,
                      const ushort4* __restrict__ T2, float4* __restrict__ acc) {
    int node = blockIdx.x * 16 + (threadIdx.x >> 4);
    int lane = threadIdx.x & 15;
    if (node >= N_NODES) return;
    unsigned beg = row_ptr[node], end = row_ptr[node + 1];
    GATHER_CORE(T2)
    size_t o = (size_t)node * D4 + lane;
    float4 l2 = bf4_to_f4(T2[o]);
    float4 c = acc[o];
    acc[o] = make_float4((c.x + l2.x + ax) * 0.25f, (c.y + l2.y + ay) * 0.25f,
                         (c.z + l2.z + az) * 0.25f, (c.w + l2.w + aw) * 0.25f);
}

extern "C" void kernel_launch(void* const* d_in, const int* in_sizes, int n_in,
                              void* d_out, int out_size, void* d_ws, size_t ws_size,
                              hipStream_t stream) {
    const float* emb = (const float*)d_in[0];
    const int* ei = (const int*)d_in[1];
    const float* attr = (const float*)d_in[2];

    float* out_emb = (float*)d_out;
    float* out_acc = out_emb + (size_t)N_NODES * 64;

    char* ws = (char*)d_ws;
    size_t off = 0;
    auto alloc = [&](size_t bytes) -> void* {
        void* p = ws + off;
        off += (bytes + 255) & ~(size_t)255;
        return p;
    };
    unsigned* cnt_t   = (unsigned*)alloc((size_t)NBK * 4);
    unsigned* cnt_f   = (unsigned*)alloc((size_t)NBK * 4);
    size_t zero_bytes = off;
    unsigned* base_t  = (unsigned*)alloc((size_t)(NBK + 1) * 4);
    unsigned* base_f  = (unsigned*)alloc((size_t)(NBK + 1) * 4);
    unsigned* pos_t   = (unsigned*)alloc((size_t)NBK * 4);
    unsigned* pos_f   = (unsigned*)alloc((size_t)NBK * 4);
    unsigned* row_ptr = (unsigned*)alloc((size_t)(N_NODES + 1) * 4);
    float* s_from_inv = (float*)   alloc((size_t)N_NODES * 4);
    uint2* bt         = (uint2*)   alloc((size_t)N_EDGES * 8);   // dead after bucket_csr_t
    uint2* bf         = (uint2*)   alloc((size_t)N_EDGES * 8);   // becomes slots
    uint2* slots      = bf;        // bf fully consumed by bucket_sum_f before slots written
    ushort4* T1       = (ushort4*) alloc((size_t)N_NODES * 64 * 2);
    // aliases inside the dead bt region:
    ushort4* T2     = (ushort4*)bt;                                   // layer-2 output table
    ushort4* emb_bf = (ushort4*)((char*)bt + (size_t)N_NODES * 128);  // bf16 emb table
    (void)ws_size;

    hipMemsetAsync(d_ws, 0, zero_bytes, stream);

    hist_kernel<<<256, 256, 0, stream>>>(ei, cnt_t, cnt_f);
    scan_buckets<<<1, 512, 0, stream>>>(cnt_t, cnt_f, base_t, base_f, pos_t, pos_f);
    const int pblocks = (N_EDGES + PTILE - 1) / PTILE;
    partition<<<pblocks, 256, 0, stream>>>(ei, attr, pos_t, pos_f, bt, bf);
    bucket_sum_f<<<NBK, 256, 0, stream>>>(base_f, bf, s_from_inv);
    bucket_csr_t<<<NBK, 256, 0, stream>>>(base_t, bt, s_from_inv, row_ptr, slots);

    const int vgrid = (N_NODES * D4 + 255) / 256;
    emb_cvt<<<vgrid, 256, 0, stream>>>((const float4*)emb, (float4*)out_emb, emb_bf);

    const int pgrid = (N_NODES * 16 + 255) / 256;
    prop1<<<pgrid, 256, 0, stream>>>(row_ptr, slots, emb_bf, (const float4*)emb,
                                     T1, (float4*)out_acc);
    prop2<<<pgrid, 256, 0, stream>>>(row_ptr, slots, T1, T2);
    prop3<<<pgrid, 256, 0, stream>>>(row_ptr, slots, T2, (float4*)out_acc);
}

// Round 9
// 394.243 us; speedup vs baseline: 1.5334x; 1.0194x over previous
//
#include <hip/hip_runtime.h>
#include <math.h>
#include <hip/hip_fp16.h>

#define N_NODES 100000
#define N_EDGES 3200000
#define D4 16
#define EPS 1e-16f
#define BSH 8
#define BNODES 256
#define NBK 391              /* ceil(100000/256) */
#define PE 16
#define PTILE (PE * 256)

static __device__ __forceinline__ unsigned short f_to_bf(float f) {
    unsigned u = __float_as_uint(f);
    unsigned r = (u + 0x7FFFu + ((u >> 16) & 1u)) >> 16;  // RNE
    return (unsigned short)r;
}
static __device__ __forceinline__ float bf_to_f(unsigned short b) {
    return __uint_as_float((unsigned)b << 16);
}
static __device__ __forceinline__ float4 bf4_to_f4(ushort4 u) {
    return make_float4(bf_to_f(u.x), bf_to_f(u.y), bf_to_f(u.z), bf_to_f(u.w));
}
static __device__ __forceinline__ ushort4 f4_to_bf4(float x, float y, float z, float w) {
    return make_ushort4(f_to_bf(x), f_to_bf(y), f_to_bf(z), f_to_bf(w));
}

// ---- Phase A: exact bucket histograms (per-block LDS, one flush per block) ----
__global__ void hist_kernel(const int* __restrict__ ei,
                            unsigned* __restrict__ cnt_t, unsigned* __restrict__ cnt_f) {
    __shared__ unsigned ht[NBK], hf[NBK];
    for (int i = threadIdx.x; i < NBK; i += 256) { ht[i] = 0; hf[i] = 0; }
    __syncthreads();
    int stride = gridDim.x * blockDim.x;
    for (int e = blockIdx.x * blockDim.x + threadIdx.x; e < N_EDGES; e += stride) {
        atomicAdd(&hf[((unsigned)ei[e]) >> BSH], 1u);
        atomicAdd(&ht[((unsigned)ei[N_EDGES + e]) >> BSH], 1u);
    }
    __syncthreads();
    for (int i = threadIdx.x; i < NBK; i += 256) {
        if (ht[i]) atomicAdd(&cnt_t[i], ht[i]);
        if (hf[i]) atomicAdd(&cnt_f[i], hf[i]);
    }
}

// ---- Phase B: exclusive scan of bucket counts -> bases + reservation cursors ----
__global__ void scan_buckets(const unsigned* __restrict__ cnt_t, const unsigned* __restrict__ cnt_f,
                             unsigned* __restrict__ base_t, unsigned* __restrict__ base_f,
                             unsigned* __restrict__ pos_t, unsigned* __restrict__ pos_f) {
    __shared__ unsigned sc[512];
    int tid = threadIdx.x;
    unsigned own = (tid < NBK) ? cnt_t[tid] : 0u;
    sc[tid] = own;
    __syncthreads();
    for (int o = 1; o < 512; o <<= 1) {
        unsigned v = (tid >= o) ? sc[tid - o] : 0u;
        __syncthreads();
        sc[tid] += v;
        __syncthreads();
    }
    if (tid < NBK) { unsigned ex = sc[tid] - own; base_t[tid] = ex; pos_t[tid] = ex; }
    if (tid == NBK - 1) base_t[NBK] = sc[tid];
    __syncthreads();
    own = (tid < NBK) ? cnt_f[tid] : 0u;
    sc[tid] = own;
    __syncthreads();
    for (int o = 1; o < 512; o <<= 1) {
        unsigned v = (tid >= o) ? sc[tid - o] : 0u;
        __syncthreads();
        sc[tid] += v;
        __syncthreads();
    }
    if (tid < NBK) { unsigned ex = sc[tid] - own; base_f[tid] = ex; pos_f[tid] = ex; }
    if (tid == NBK - 1) base_f[NBK] = sc[tid];
}

// ---- Phase C: single-pass partition (register-staged tile) into dst-bucketed
// bt (uint2: f|t_local<<17, ex f32) and src-bucketed bf (u32: f_local<<16 | f16(ex)) ----
__global__ void partition(const int* __restrict__ ei, const float* __restrict__ attr,
                          unsigned* __restrict__ pos_t, unsigned* __restrict__ pos_f,
                          uint2* __restrict__ bt, unsigned* __restrict__ bf) {
    __shared__ unsigned ht[NBK], hf[NBK];
    for (int i = threadIdx.x; i < NBK; i += 256) { ht[i] = 0; hf[i] = 0; }
    __syncthreads();
    const int tile = blockIdx.x * PTILE;
    unsigned fv[PE], tv[PE];
    float xv[PE];
    #pragma unroll
    for (int k = 0; k < PE; ++k) {
        int e = tile + k * 256 + threadIdx.x;
        if (e < N_EDGES) {
            fv[k] = (unsigned)ei[e];
            tv[k] = (unsigned)ei[N_EDGES + e];
            xv[k] = __expf(attr[e]);
            atomicAdd(&ht[tv[k] >> BSH], 1u);
            atomicAdd(&hf[fv[k] >> BSH], 1u);
        } else {
            tv[k] = 0xFFFFFFFFu;
        }
    }
    __syncthreads();
    for (int i = threadIdx.x; i < NBK; i += 256) {
        unsigned c = ht[i];
        if (c) ht[i] = atomicAdd(&pos_t[i], c);
        c = hf[i];
        if (c) hf[i] = atomicAdd(&pos_f[i], c);
    }
    __syncthreads();
    #pragma unroll
    for (int k = 0; k < PE; ++k) {
        if (tv[k] != 0xFFFFFFFFu) {
            unsigned p = atomicAdd(&ht[tv[k] >> BSH], 1u);
            bt[p] = make_uint2(fv[k] | ((tv[k] & 255u) << 17), __float_as_uint(xv[k]));
            unsigned q = atomicAdd(&hf[fv[k] >> BSH], 1u);
            bf[q] = ((fv[k] & 255u) << 16) | (unsigned)__half_as_ushort(__float2half(xv[k]));
        }
    }
}

// ---- Phase D: per-src-bucket sums -> s_from_inv (LDS only) ----
__global__ void bucket_sum_f(const unsigned* __restrict__ base_f, const unsigned* __restrict__ bf,
                             float* __restrict__ s_from_inv) {
    __shared__ float s[BNODES];
    int b = blockIdx.x, tid = threadIdx.x;
    s[tid] = 0.f;
    __syncthreads();
    unsigned lo = base_f[b], hi = base_f[b + 1];
    for (unsigned i = lo + tid; i < hi; i += 256) {
        unsigned u = bf[i];
        atomicAdd(&s[u >> 16], __half2float(__ushort_as_half((unsigned short)(u & 0xFFFFu))));
    }
    __syncthreads();
    int node = b * BNODES + tid;
    if (node < N_NODES) s_from_inv[node] = rsqrtf(s[tid] + EPS);
}

// ---- Phase E: per-dst-bucket: exact dense CSR (row_ptr) + final edge weights ----
__global__ void bucket_csr_t(const unsigned* __restrict__ base_t, const uint2* __restrict__ bt,
                             const float* __restrict__ s_from_inv,
                             unsigned* __restrict__ row_ptr, uint2* __restrict__ slots) {
    __shared__ unsigned cnt[BNODES];
    __shared__ float sto[BNODES];
    __shared__ unsigned sc[BNODES];
    __shared__ float rs[BNODES];
    __shared__ unsigned cur[BNODES];
    int b = blockIdx.x, tid = threadIdx.x;
    cnt[tid] = 0;
    sto[tid] = 0.f;
    __syncthreads();
    unsigned lo = base_t[b], hi = base_t[b + 1];
    for (unsigned i = lo + tid; i < hi; i += 256) {
        uint2 u = bt[i];
        unsigned tl = u.x >> 17;
        atomicAdd(&cnt[tl], 1u);
        atomicAdd(&sto[tl], __uint_as_float(u.y));
    }
    __syncthreads();
    unsigned own = cnt[tid];
    sc[tid] = own;
    __syncthreads();
    for (int o = 1; o < 256; o <<= 1) {
        unsigned v = (tid >= o) ? sc[tid - o] : 0u;
        __syncthreads();
        sc[tid] += v;
        __syncthreads();
    }
    unsigned excl = sc[tid] - own;
    int node = b * BNODES + tid;
    if (node < N_NODES) row_ptr[node] = lo + excl;
    if (b == NBK - 1 && tid == 0) row_ptr[N_NODES] = N_EDGES;
    rs[tid] = rsqrtf(sto[tid] + EPS);
    cur[tid] = lo + excl;
    __syncthreads();
    for (unsigned i = lo + tid; i < hi; i += 256) {
        uint2 u = bt[i];
        unsigned tl = u.x >> 17;
        unsigned f = u.x & 0x1FFFFu;
        float w = __uint_as_float(u.y) * rs[tl] * s_from_inv[f];
        unsigned p = atomicAdd(&cur[tl], 1u);
        slots[p] = make_uint2(f, __float_as_uint(w));
    }
}

// ---- emb -> bf16 table + out_emb copy ----
__global__ void emb_cvt(const float4* __restrict__ emb4, float4* __restrict__ out_emb4,
                        ushort4* __restrict__ emb_bf) {
    int i = blockIdx.x * blockDim.x + threadIdx.x;
    if (i >= N_NODES * D4) return;
    float4 v = emb4[i];
    out_emb4[i] = v;
    emb_bf[i] = f4_to_bf4(v.x, v.y, v.z, v.w);
}

// 4x-unrolled bf16 gather accumulation core (16 lanes per node)
#define GATHER_CORE(TABLE)                                                        \
    float ax = 0.f, ay = 0.f, az = 0.f, aw = 0.f;                                 \
    float bx = 0.f, by = 0.f, bz = 0.f, bw = 0.f;                                 \
    unsigned k = beg;                                                             \
    for (; k + 4 <= end; k += 4) {                                                \
        uint2 s0 = slots[k], s1 = slots[k + 1], s2 = slots[k + 2], s3 = slots[k + 3]; \
        ushort4 r0 = TABLE[(size_t)s0.x * D4 + lane];                             \
        ushort4 r1 = TABLE[(size_t)s1.x * D4 + lane];                             \
        ushort4 r2 = TABLE[(size_t)s2.x * D4 + lane];                             \
        ushort4 r3 = TABLE[(size_t)s3.x * D4 + lane];                             \
        float w0 = __uint_as_float(s0.y), w1 = __uint_as_float(s1.y);             \
        float w2 = __uint_as_float(s2.y), w3 = __uint_as_float(s3.y);             \
        float4 v0 = bf4_to_f4(r0), v1 = bf4_to_f4(r1);                            \
        float4 v2 = bf4_to_f4(r2), v3 = bf4_to_f4(r3);                            \
        ax = fmaf(w0, v0.x, ax); ay = fmaf(w0, v0.y, ay);                         \
        az = fmaf(w0, v0.z, az); aw = fmaf(w0, v0.w, aw);                         \
        bx = fmaf(w1, v1.x, bx); by = fmaf(w1, v1.y, by);                         \
        bz = fmaf(w1, v1.z, bz); bw = fmaf(w1, v1.w, bw);                         \
        ax = fmaf(w2, v2.x, ax); ay = fmaf(w2, v2.y, ay);                         \
        az = fmaf(w2, v2.z, az); aw = fmaf(w2, v2.w, aw);                         \
        bx = fmaf(w3, v3.x, bx); by = fmaf(w3, v3.y, by);                         \
        bz = fmaf(w3, v3.z, bz); bw = fmaf(w3, v3.w, bw);                         \
    }                                                                             \
    for (; k < end; ++k) {                                                        \
        uint2 sl = slots[k];                                                      \
        float w = __uint_as_float(sl.y);                                          \
        float4 v = bf4_to_f4(TABLE[(size_t)sl.x * D4 + lane]);                    \
        ax = fmaf(w, v.x, ax); ay = fmaf(w, v.y, ay);                             \
        az = fmaf(w, v.z, az); aw = fmaf(w, v.w, aw);                             \
    }                                                                             \
    ax += bx; ay += by; az += bz; aw += bw;

// ---- Layer 1: bf16 emb gather; T1 = bf16(l1); acc = emb + l1 (f32, write-only) ----
__global__ void prop1(const unsigned* __restrict__ row_ptr, const uint2* __restrict__ slots,
                      const ushort4* __restrict__ emb_bf, const float4* __restrict__ emb4,
                      ushort4* __restrict__ T1, float4* __restrict__ acc) {
    int node = blockIdx.x * 16 + (threadIdx.x >> 4);
    int lane = threadIdx.x & 15;
    if (node >= N_NODES) return;
    unsigned beg = row_ptr[node], end = row_ptr[node + 1];
    GATHER_CORE(emb_bf)
    size_t o = (size_t)node * D4 + lane;
    T1[o] = f4_to_bf4(ax, ay, az, aw);
    float4 e = emb4[o];
    acc[o] = make_float4(e.x + ax, e.y + ay, e.z + az, e.w + aw);
}

// ---- Layer 2: bf16 gather from T1; writes T2 only (acc deferred to layer 3) ----
__global__ void prop2(const unsigned* __restrict__ row_ptr, const uint2* __restrict__ slots,
                      const ushort4* __restrict__ T1, ushort4* __restrict__ T2) {
    int node = blockIdx.x * 16 + (threadIdx.x >> 4);
    int lane = threadIdx.x & 15;
    if (node >= N_NODES) return;
    unsigned beg = row_ptr[node], end = row_ptr[node + 1];
    GATHER_CORE(T1)
    size_t o = (size_t)node * D4 + lane;
    T2[o] = f4_to_bf4(ax, ay, az, aw);
}

// ---- Layer 3: bf16 gather from T2; acc = (acc + T2[o] + l3) * 0.25 ----
__global__ void prop3(const unsigned* __restrict__ row_ptr, const uint2* __restrict__ slots,
                      const ushort4* __restrict__ T2, float4* __restrict__ acc) {
    int node = blockIdx.x * 16 + (threadIdx.x >> 4);
    int lane = threadIdx.x & 15;
    if (node >= N_NODES) return;
    unsigned beg = row_ptr[node], end = row_ptr[node + 1];
    GATHER_CORE(T2)
    size_t o = (size_t)node * D4 + lane;
    float4 l2 = bf4_to_f4(T2[o]);
    float4 c = acc[o];
    acc[o] = make_float4((c.x + l2.x + ax) * 0.25f, (c.y + l2.y + ay) * 0.25f,
                         (c.z + l2.z + az) * 0.25f, (c.w + l2.w + aw) * 0.25f);
}

extern "C" void kernel_launch(void* const* d_in, const int* in_sizes, int n_in,
                              void* d_out, int out_size, void* d_ws, size_t ws_size,
                              hipStream_t stream) {
    const float* emb = (const float*)d_in[0];
    const int* ei = (const int*)d_in[1];
    const float* attr = (const float*)d_in[2];

    float* out_emb = (float*)d_out;
    float* out_acc = out_emb + (size_t)N_NODES * 64;

    char* ws = (char*)d_ws;
    size_t off = 0;
    auto alloc = [&](size_t bytes) -> void* {
        void* p = ws + off;
        off += (bytes + 255) & ~(size_t)255;
        return p;
    };
    unsigned* cnt_t   = (unsigned*)alloc((size_t)NBK * 4);
    unsigned* cnt_f   = (unsigned*)alloc((size_t)NBK * 4);
    size_t zero_bytes = off;
    unsigned* base_t  = (unsigned*)alloc((size_t)(NBK + 1) * 4);
    unsigned* base_f  = (unsigned*)alloc((size_t)(NBK + 1) * 4);
    unsigned* pos_t   = (unsigned*)alloc((size_t)NBK * 4);
    unsigned* pos_f   = (unsigned*)alloc((size_t)NBK * 4);
    unsigned* row_ptr = (unsigned*)alloc((size_t)(N_NODES + 1) * 4);
    float* s_from_inv = (float*)   alloc((size_t)N_NODES * 4);
    uint2* bt         = (uint2*)   alloc((size_t)N_EDGES * 8);   // dead after bucket_csr_t
    unsigned* bfa     = (unsigned*)alloc((size_t)N_EDGES * 4);   // becomes dead after bucket_sum_f
    uint2* slots      = (uint2*)   alloc((size_t)N_EDGES * 8);
    ushort4* T1       = (ushort4*) alloc((size_t)N_NODES * 64 * 2);
    // aliases inside the dead bt region:
    ushort4* T2     = (ushort4*)bt;                                   // layer-2 output table
    ushort4* emb_bf = (ushort4*)((char*)bt + (size_t)N_NODES * 128);  // bf16 emb table
    (void)ws_size;

    hipMemsetAsync(d_ws, 0, zero_bytes, stream);

    hist_kernel<<<256, 256, 0, stream>>>(ei, cnt_t, cnt_f);
    scan_buckets<<<1, 512, 0, stream>>>(cnt_t, cnt_f, base_t, base_f, pos_t, pos_f);
    const int pblocks = (N_EDGES + PTILE - 1) / PTILE;
    partition<<<pblocks, 256, 0, stream>>>(ei, attr, pos_t, pos_f, bt, bfa);
    bucket_sum_f<<<NBK, 256, 0, stream>>>(base_f, bfa, s_from_inv);
    bucket_csr_t<<<NBK, 256, 0, stream>>>(base_t, bt, s_from_inv, row_ptr, slots);

    const int vgrid = (N_NODES * D4 + 255) / 256;
    emb_cvt<<<vgrid, 256, 0, stream>>>((const float4*)emb, (float4*)out_emb, emb_bf);

    const int pgrid = (N_NODES * 16 + 255) / 256;
    prop1<<<pgrid, 256, 0, stream>>>(row_ptr, slots, emb_bf, (const float4*)emb,
                                     T1, (float4*)out_acc);
    prop2<<<pgrid, 256, 0, stream>>>(row_ptr, slots, T1, T2);
    prop3<<<pgrid, 256, 0, stream>>>(row_ptr, slots, T2, (float4*)out_acc);
}